// Round 5
// baseline (491.913 us; speedup 1.0000x reference)
//
#include <hip/hip_runtime.h>
#include <hip/hip_bf16.h>

typedef __bf16 bf16_t;
typedef __attribute__((ext_vector_type(8))) __bf16 bf16x8;
typedef __attribute__((ext_vector_type(4))) __bf16 bf16x4;
typedef __attribute__((ext_vector_type(4))) float f32x4;

#define NPOS 38416  // 196*196
#define KSTR 40     // kf row stride (80B = 20 banks -> 2-way, free)
#define VSTR 232    // vts row stride (464B -> 2-way)
#define PSTR 152    // pb row stride (304B = 76 dw; 76%32=12 -> 2-way, 16B-aligned)

__device__ __forceinline__ void async_copy16(const bf16_t* g, bf16_t* l) {
  __builtin_amdgcn_global_load_lds((const __attribute__((address_space(1))) void*)g,
                                   (__attribute__((address_space(3))) void*)l, 16, 0, 0);
}

// ---------------- cast x -> bf16 ----------------
__global__ __launch_bounds__(256) void cast_x_kernel(const float* __restrict__ x,
                                                     bf16_t* __restrict__ xb, int n4) {
  int i = blockIdx.x * 256 + threadIdx.x;
  if (i < n4) {
    float4 v = ((const float4*)x)[i];
    bf16x4 o;
    o[0] = (bf16_t)v.x; o[1] = (bf16_t)v.y; o[2] = (bf16_t)v.z; o[3] = (bf16_t)v.w;
    ((bf16x4*)xb)[i] = o;
  }
}

// ---------------- transpose + cast W: src[K][Ncols] f32 -> dst[Ncols][K] bf16 ----------------
__global__ __launch_bounds__(256) void transpose_cast_kernel(const float* __restrict__ src,
                                                             bf16_t* __restrict__ dst,
                                                             int K, int Ncols) {
  __shared__ float tile[32][33];
  int t = threadIdx.x;
  int tx = t & 31, ty = t >> 5;
  int bx = blockIdx.x, by = blockIdx.y;
  for (int r = ty; r < 32; r += 8)
    tile[r][tx] = src[(size_t)(by * 32 + r) * Ncols + bx * 32 + tx];
  __syncthreads();
  for (int r = ty; r < 32; r += 8)
    dst[(size_t)(bx * 32 + r) * K + by * 32 + tx] = (bf16_t)tile[tx][r];
}

// ---------------- transposed bias gather: bias_t[h][j][i] = rpk[rel_idx[i][j]][h] ----------------
// thread = (h, j); loops i writing a contiguous 784B run; rel_idx reads coalesce across lanes.
__global__ __launch_bounds__(256) void bias_gather_t_kernel(const float* __restrict__ rpk,
                                                            const int* __restrict__ rel_idx,
                                                            float* __restrict__ bias_t) {
  int tg = blockIdx.x * 256 + threadIdx.x;
  if (tg >= 32 * 196) return;
  int h = tg / 196, j = tg - h * 196;
  float* dst = bias_t + (size_t)tg * 196;
  for (int i = 0; i < 196; ++i) {
    int idx = rel_idx[i * 196 + j];
    dst[i] = rpk[idx * 32 + h];
  }
}

// ---------------- 128x128 bf16 GEMM, B^T input, K=1024 ----------------
// A: direct global->register (wave-private rows, L1-served), prefetched one
// K-tile ahead. B: LDS double-buffer via global_load_lds, one barrier/iter,
// 16B-chunk XOR swizzle. Grid XCD-banded: m = mi*8 + xcd, n fastest within XCD
// (A-tile reused by NT consecutive same-XCD blocks, stays L2-resident).
template <int MODE>
__global__ __launch_bounds__(256, 4) void gemm_bt_kernel(
    const bf16_t* __restrict__ A, const bf16_t* __restrict__ Bt,
    bf16_t* __restrict__ qo, bf16_t* __restrict__ ko, bf16_t* __restrict__ vto,
    float* __restrict__ fo, const float* __restrict__ bp, int NT) {
  constexpr int K = 1024;
  __shared__ alignas(16) bf16_t Bsh[2][128 * 32];
  const int t = threadIdx.x;
  const int lane = t & 63;
  const int quad = lane >> 4;
  const int l16 = lane & 15;
  const int wave = t >> 6;

  const int L = blockIdx.x;
  const int xcd = L & 7, ii = L >> 3;
  const int n_t = ii % NT, mi = ii / NT;
  const int m_t = mi * 8 + xcd;
  if (m_t >= 98) return;
  const int m0 = m_t * 128, n0 = n_t * 128;
  const int wr = (wave >> 1) * 64, wc = (wave & 1) * 64;

  // B staging: 512 chunks of 16B, 2 per thread; XOR-swizzled source chunk
  const int c0 = t, c1 = t + 256;
  const bf16_t* gB0 = Bt + (size_t)(n0 + (c0 >> 2)) * K + ((c0 & 3) ^ ((c0 >> 3) & 3)) * 8;
  const bf16_t* gB1 = Bt + (size_t)(n0 + (c1 >> 2)) * K + ((c1 & 3) ^ ((c1 >> 3) & 3)) * 8;

  const int qa = quad ^ ((l16 >> 1) & 3);
  const bf16_t* aRow = A + (size_t)(m0 + wr + l16) * K + quad * 8;

  const f32x4 vzero = {0.f, 0.f, 0.f, 0.f};
  f32x4 acc[4][4];
#pragma unroll
  for (int i = 0; i < 4; ++i)
#pragma unroll
    for (int j = 0; j < 4; ++j) acc[i][j] = vzero;

  bf16x8 af[4];
#pragma unroll
  for (int i = 0; i < 4; ++i) af[i] = *(const bf16x8*)(aRow + i * 16 * K);
  async_copy16(gB0, &Bsh[0][c0 * 8]);
  async_copy16(gB1, &Bsh[0][c1 * 8]);

#pragma unroll 2
  for (int it = 0; it < K / 32; ++it) {
    __syncthreads();  // drains B-DMA issued one full iteration ago
    bf16x8 afn[4];
    if (it + 1 < K / 32) {
      const int kt = (it + 1) * 32;
      bf16_t* nb = &Bsh[(it + 1) & 1][0];
      async_copy16(gB0 + kt, nb + c0 * 8);
      async_copy16(gB1 + kt, nb + c1 * 8);
#pragma unroll
      for (int i = 0; i < 4; ++i) afn[i] = *(const bf16x8*)(aRow + i * 16 * K + kt);
    } else {
#pragma unroll
      for (int i = 0; i < 4; ++i) afn[i] = af[i];
    }
    const bf16_t* Bs = &Bsh[it & 1][0];
    bf16x8 bfr[4];
#pragma unroll
    for (int j = 0; j < 4; ++j)
      bfr[j] = *(const bf16x8*)(Bs + (wc + j * 16 + l16) * 32 + qa * 8);
#pragma unroll
    for (int i = 0; i < 4; ++i)
#pragma unroll
      for (int j = 0; j < 4; ++j)
        acc[i][j] = __builtin_amdgcn_mfma_f32_16x16x32_bf16(af[i], bfr[j], acc[i][j], 0, 0, 0);
#pragma unroll
    for (int i = 0; i < 4; ++i) af[i] = afn[i];
  }

  if (MODE == 0) {
    const float qscale = 0.17677669529663687f;  // 1/sqrt(32)
    const int which = n0 >> 10;                 // uniform per block
#pragma unroll
    for (int i = 0; i < 4; ++i) {
      const int rb = m0 + wr + i * 16 + quad * 4;
#pragma unroll
      for (int j = 0; j < 4; ++j) {
        const int c = n0 + wc + j * 16 + l16;
        const int h = (c >> 5) & 31, d = c & 31;
#pragma unroll
        for (int r = 0; r < 4; ++r) {
          const int rg = rb + r;
          const int b = rg / 196, n = rg - b * 196;
          const float v = acc[i][j][r];
          if (which == 0)
            qo[(((size_t)b * 32 + h) * 196 + n) * 32 + d] = (bf16_t)(v * qscale);
          else if (which == 1)
            ko[(((size_t)b * 32 + h) * 196 + n) * 32 + d] = (bf16_t)v;
          else
            vto[(((size_t)b * 32 + h) * 32 + d) * 196 + n] = (bf16_t)v;
        }
      }
    }
  } else {
#pragma unroll
    for (int i = 0; i < 4; ++i) {
      const int rb = m0 + wr + i * 16 + quad * 4;
#pragma unroll
      for (int j = 0; j < 4; ++j) {
        const int c = n0 + wc + j * 16 + l16;
        const float bias_c = bp[c];
#pragma unroll
        for (int r = 0; r < 4; ++r)
          fo[(size_t)(rb + r) * 1024 + c] = acc[i][j][r] + bias_c;
      }
    }
  }
}

// ---------------- attention: one block per (b,h); wave-private, barrier-free main loop ----------------
// Bias enters as the MFMA C-operand (bias_t[h][j][i] -> C-layout float4 loads).
// No max-subtraction (|scores| bounded ~15). P stored unnormalized in a
// HALF-width per-wave buffer, PV in two col-phases (in-order DS ops make the
// phase-2 overwrite safe). LDS 50.9 KB -> 3 blocks/CU.
__global__ __launch_bounds__(256, 3) void attn_kernel(
    const bf16_t* __restrict__ q, const bf16_t* __restrict__ kmat,
    const bf16_t* __restrict__ vtg, const float* __restrict__ bias_t,
    bf16_t* __restrict__ attn_out) {
  __shared__ alignas(16) bf16_t kf[208 * KSTR];     // K rows [n][d]; rows>=196 garbage (masked)
  __shared__ alignas(16) bf16_t vts[32 * VSTR];     // V^T [d][n], cols>=196 zero
  __shared__ alignas(16) bf16_t pb[4][16 * PSTR];   // per-wave half-width P

  const int t = threadIdx.x;
  const int lane = t & 63;
  const int quad = lane >> 4, l16 = lane & 15;
  const int wave = t >> 6;
  const int bh = blockIdx.x;
  const int b = bh >> 5, h = bh & 31;
  const bf16_t* qg = q + (size_t)bh * (196 * 32);
  const bf16_t* kg = kmat + (size_t)bh * (196 * 32);
  const bf16_t* vg = vtg + (size_t)bh * (32 * 196);
  const float* bg = bias_t + (size_t)h * NPOS;  // [j][i]

  {
    const uint4* src = (const uint4*)kg;
    uint4* dst = (uint4*)kf;  // row r chunks -> uint4 slots r*5+0..3 (KSTR=40)
    for (int c = t; c < 784; c += 256) dst[(c >> 2) * 5 + (c & 3)] = src[c];
    const uint2 z2 = {0u, 0u};
    for (int i = t; i < 1792; i += 256) {  // 32 rows x 56 x 8B (stride VSTR)
      int d = i / 56, c = i - d * 56;
      uint2 val = (c < 49) ? ((const uint2*)(vg + d * 196))[c] : z2;
      ((uint2*)(vts + d * VSTR))[c] = val;
    }
  }
  __syncthreads();

  const f32x4 vzero = {0.f, 0.f, 0.f, 0.f};
  bf16_t* pw = &pb[wave][0];

  for (int ch = wave; ch < 13; ch += 4) {
    const int q0 = ch * 16;
    int qrow = q0 + l16;
    if (qrow > 195) qrow = 195;  // clamp; junk rows never stored
    const bf16x8 aq = *(const bf16x8*)(qg + qrow * 32 + quad * 8);

    // bias C-fragments: cb[ct][r] = bias_t[h][col][i0+r]
    int i0 = q0 + quad * 4;
    if (i0 > 192) i0 = 192;  // clamp (junk rows masked later)
    f32x4 cb[13];
#pragma unroll
    for (int ct = 0; ct < 13; ++ct) {
      int colc = ct * 16 + l16;
      if (colc > 195) colc = 195;  // clamp (masked cols overwritten below)
      cb[ct] = *(const f32x4*)(bg + (size_t)colc * 196 + i0);
    }

    f32x4 s[13];
#pragma unroll
    for (int ct = 0; ct < 13; ++ct) {
      const bf16x8 bk = *(const bf16x8*)(kf + (ct * 16 + l16) * KSTR + quad * 8);
      s[ct] = __builtin_amdgcn_mfma_f32_16x16x32_bf16(aq, bk, cb[ct], 0, 0, 0);
    }
    // right-edge mask (only ct=12 has cols >= 196), then exp (no max pass)
#pragma unroll
    for (int ct = 0; ct < 13; ++ct) {
      const int col = ct * 16 + l16;
#pragma unroll
      for (int r = 0; r < 4; ++r) {
        if (col >= 196) s[ct][r] = -1e30f;
        s[ct][r] = __expf(s[ct][r]);
      }
    }
    float inv[4];
#pragma unroll
    for (int r = 0; r < 4; ++r) {
      float sum = s[0][r];
#pragma unroll
      for (int ct = 1; ct < 13; ++ct) sum += s[ct][r];
      sum += __shfl_xor(sum, 1);
      sum += __shfl_xor(sum, 2);
      sum += __shfl_xor(sum, 4);
      sum += __shfl_xor(sum, 8);
      inv[r] = 1.f / sum;
    }
    // ---- phase 1: P cols 0..127 -> pb, PV over kk=0..3 ----
#pragma unroll
    for (int ct = 0; ct < 8; ++ct) {
      const int col = ct * 16 + l16;
#pragma unroll
      for (int r = 0; r < 4; ++r) pw[(quad * 4 + r) * PSTR + col] = (bf16_t)s[ct][r];
    }
    f32x4 o[2] = {vzero, vzero};
#pragma unroll
    for (int dt = 0; dt < 2; ++dt)
#pragma unroll
      for (int kk = 0; kk < 4; ++kk) {
        const bf16x8 ap = *(const bf16x8*)(pw + l16 * PSTR + kk * 32 + quad * 8);
        const bf16x8 bv = *(const bf16x8*)(vts + (dt * 16 + l16) * VSTR + kk * 32 + quad * 8);
        o[dt] = __builtin_amdgcn_mfma_f32_16x16x32_bf16(ap, bv, o[dt], 0, 0, 0);
      }
    // ---- phase 2: P cols 128..223 -> pb (local 0..95), PV over kk=4..6 ----
    // same-wave DS ops are in-order: phase-1 reads complete before these writes
#pragma unroll
    for (int ct = 8; ct < 13; ++ct) {
      const int col = (ct - 8) * 16 + l16;
#pragma unroll
      for (int r = 0; r < 4; ++r) pw[(quad * 4 + r) * PSTR + col] = (bf16_t)s[ct][r];
    }
    if (lane < 32) {  // zero local cols 80..95 (global 208..223)
      const bf16x8 z8 = {};
      *(bf16x8*)(pw + (lane >> 1) * PSTR + 80 + (lane & 1) * 8) = z8;
    }
#pragma unroll
    for (int dt = 0; dt < 2; ++dt)
#pragma unroll
      for (int kk = 0; kk < 3; ++kk) {
        const bf16x8 ap = *(const bf16x8*)(pw + l16 * PSTR + kk * 32 + quad * 8);
        const bf16x8 bv = *(const bf16x8*)(vts + (dt * 16 + l16) * VSTR + 128 + kk * 32 + quad * 8);
        o[dt] = __builtin_amdgcn_mfma_f32_16x16x32_bf16(ap, bv, o[dt], 0, 0, 0);
      }
#pragma unroll
    for (int dt = 0; dt < 2; ++dt) {
      const int d = dt * 16 + l16;
#pragma unroll
      for (int r = 0; r < 4; ++r) {
        const int n = q0 + quad * 4 + r;
        if (n < 196)
          attn_out[(((size_t)b * 196 + n) * 32 + h) * 32 + d] = (bf16_t)(o[dt][r] * inv[r]);
      }
    }
  }
}

extern "C" void kernel_launch(void* const* d_in, const int* in_sizes, int n_in,
                              void* d_out, int out_size, void* d_ws, size_t ws_size,
                              hipStream_t stream) {
  (void)in_sizes; (void)n_in; (void)out_size; (void)ws_size;
  const float* x = (const float*)d_in[0];
  const float* Wqkv = (const float*)d_in[1];
  const float* Wproj = (const float*)d_in[2];
  const float* bproj = (const float*)d_in[3];
  const float* rpk = (const float*)d_in[4];
  const int* rel_idx = (const int*)d_in[5];
  float* out = (float*)d_out;

  char* ws = (char*)d_ws;
  bf16_t* xb = (bf16_t*)(ws + 0);                  // 25,690,112 B ; reused as attn_out
  bf16_t* wqkvT = (bf16_t*)(ws + 25690112);        //  6,291,456 B
  bf16_t* wprojT = (bf16_t*)(ws + 31981568);       //  2,097,152 B
  bf16_t* q = (bf16_t*)(ws + 34078720);            // 25,690,112 B
  bf16_t* kk = (bf16_t*)(ws + 59768832);           // 25,690,112 B
  bf16_t* vt = (bf16_t*)(ws + 85458944);           // 25,690,112 B
  float* bias_t = (float*)(ws + 111149056);        //  4,917,248 B  (total ~116 MB)
  bf16_t* attn = xb;                               // xb is dead after GEMM1

  cast_x_kernel<<<12544, 256, 0, stream>>>(x, xb, 12845056 / 4);
  transpose_cast_kernel<<<dim3(96, 32), 256, 0, stream>>>(Wqkv, wqkvT, 1024, 3072);
  transpose_cast_kernel<<<dim3(32, 32), 256, 0, stream>>>(Wproj, wprojT, 1024, 1024);
  bias_gather_t_kernel<<<25, 256, 0, stream>>>(rpk, rel_idx, bias_t);
  // grids: 8 xcd * 13 mi * NT; blocks with m_t >= 98 exit immediately
  gemm_bt_kernel<0><<<8 * 13 * 24, 256, 0, stream>>>(xb, wqkvT, q, kk, vt, nullptr, nullptr, 24);
  attn_kernel<<<2048, 256, 0, stream>>>(q, kk, vt, bias_t, attn);
  gemm_bt_kernel<1><<<8 * 13 * 8, 256, 0, stream>>>(attn, wprojT, nullptr, nullptr, nullptr, out, bproj, 8);
}